// Round 5
// baseline (342.035 us; speedup 1.0000x reference)
//
#include <hip/hip_runtime.h>
#include <math.h>

#define B_  16
#define C_  64
#define HW_ 128
#define E_  5
#define PLANE 16640   // 128 rows * 130 padded cols, in 16B units, per (b,g,qq) plane

typedef __bf16  bf16x8 __attribute__((ext_vector_type(8)));
typedef float   f32x4  __attribute__((ext_vector_type(4)));

// ---- ws byte offsets ----
// wEffB: [e(5)][g(2)][tap(9)][q(4)][co(64)][j(8)] ushort = 184320 shorts
#define WS_WEFFB   0
#define WS_BIAS    368640      // float[5*64]
#define WS_POOL    369920      // float[16*64] (memset 0 each call)
#define WS_Z       374016      // float[16]    (memset 0 each call)
#define WS_EIDX    374080      // int[16]
#define WS_XT      374144      // bf16 x_t, col-padded: [b][g][qq][row 128][pcol 130][8ci]
                               // = 16*8*16640 uint4 = 34,078,720 B  (total ~34.5MB)

typedef const __attribute__((address_space(1))) uint4* gas_u4;
typedef __attribute__((address_space(3))) uint4*       las_u4;

static __device__ __forceinline__ void glds16(const void* g, void* l) {
    __builtin_amdgcn_global_load_lds((gas_u4)g, (las_u4)l, 16, 0, 0);
}

static __device__ __forceinline__ unsigned short f2bf(float f) {
    unsigned int u = __float_as_uint(f);
    unsigned int r = (u + 0x7fffu + ((u >> 16) & 1u)) >> 16;  // RNE
    return (unsigned short)r;
}

// ---------------------------------------------------------------------------
// Kernel 0: zero the left/right padded columns of x_t (ws is poisoned each call)
__global__ __launch_bounds__(256) void border_kernel(uint4* __restrict__ x_t) {
    int gid = blockIdx.x * 256 + threadIdx.x;   // 32768 items
    int plane = gid >> 8;                        // 0..127
    int rem = gid & 255;
    int row = rem >> 1, side = rem & 1;
    x_t[(size_t)plane * PLANE + row * 130 + side * 129] = make_uint4(0, 0, 0, 0);
}

// ---------------------------------------------------------------------------
// Kernel 1: LDS-free transpose fp32 NCHW -> bf16 [b][g][qq][row][pcol][8ci]
//           + pooled sums via shuffle-reduce + atomics
// grid: (b*128 + row) = 2048 blocks, 256 thr
__global__ __launch_bounds__(256) void transpose_pool_kernel(
        const float* __restrict__ x, uint4* __restrict__ x_t,
        float* __restrict__ pooled) {
    int bid = blockIdx.x;
    int b = bid >> 7, row = bid & 127;
    int t = threadIdx.x;
    const float* xb = x + (size_t)b * (64 * 16384) + row * 128;

    #pragma unroll
    for (int k = 0; k < 4; k++) {
        int idx = k * 256 + t;        // 0..1023
        int qq8 = idx >> 7;           // 0..7 = g*4+qq (wave-uniform)
        int col = idx & 127;
        float v[8];
        #pragma unroll
        for (int j = 0; j < 8; j++)
            v[j] = xb[(size_t)(qq8 * 8 + j) * 16384 + col];
        // pooling: per-ci wave reduction (64 consecutive cols per wave)
        #pragma unroll
        for (int j = 0; j < 8; j++) {
            float s = v[j];
            s += __shfl_down(s, 32);
            s += __shfl_down(s, 16);
            s += __shfl_down(s, 8);
            s += __shfl_down(s, 4);
            s += __shfl_down(s, 2);
            s += __shfl_down(s, 1);
            if ((t & 63) == 0)
                atomicAdd(&pooled[b * 64 + qq8 * 8 + j], s * (1.0f / 16384.0f));
        }
        uint4 o;
        o.x = (unsigned)f2bf(v[0]) | ((unsigned)f2bf(v[1]) << 16);
        o.y = (unsigned)f2bf(v[2]) | ((unsigned)f2bf(v[3]) << 16);
        o.z = (unsigned)f2bf(v[4]) | ((unsigned)f2bf(v[5]) << 16);
        o.w = (unsigned)f2bf(v[6]) | ((unsigned)f2bf(v[7]) << 16);
        x_t[((size_t)b * 8 + qq8) * PLANE + row * 130 + col + 1] = o;
    }
}

// ---------------------------------------------------------------------------
// Kernel 2: noisy top-1 routing (parallel over (b,e))
__global__ __launch_bounds__(256) void route_kernel(
        const float* __restrict__ pooled, const float* __restrict__ noise,
        const float* __restrict__ w_gate, const float* __restrict__ b_gate,
        const float* __restrict__ w_noise, const float* __restrict__ b_noise,
        int* __restrict__ expert_idx) {
    __shared__ float vv[16][5];
    int t = threadIdx.x;
    if (t < 80) {
        int b = t / 5, e = t % 5;
        float lg = b_gate[e], nz = b_noise[e];
        for (int c = 0; c < 64; c++) {
            float pv = pooled[b * 64 + c];
            lg += pv * w_gate[c * 5 + e];
            nz += pv * w_noise[c * 5 + e];
        }
        float sp = log1pf(expf(nz));
        vv[b][e] = lg + noise[b * 5 + e] * sp;
    }
    __syncthreads();
    if (t < 16) {
        float best = vv[t][0];
        int bi = 0;
        for (int e = 1; e < 5; e++)
            if (vv[t][e] > best) { best = vv[t][e]; bi = e; }
        expert_idx[t] = bi;
    }
}

// ---------------------------------------------------------------------------
// Kernel 3: build bf16 effective weights in MFMA A-fragment order
// layout: [e][g(2)][tap(9)][q(4)][co(64)][j(8)], ci = g*32 + q*8 + j
__global__ void build_w_kernel(const float* __restrict__ w1, const float* __restrict__ w_cd,
                               const float* __restrict__ w_hd, const float* __restrict__ w_vd,
                               const float* __restrict__ w_ad,
                               const float* __restrict__ b1, const float* __restrict__ b_cd,
                               const float* __restrict__ b_hd, const float* __restrict__ b_vd,
                               const float* __restrict__ b_ad,
                               unsigned short* __restrict__ wEffB, float* __restrict__ biasEff) {
    int gid = blockIdx.x * 256 + threadIdx.x;
    if (gid < E_ * 36864) {
        int e   = gid / 36864;
        int r   = gid % 36864;
        int g   = r / 18432;
        int r2  = r % 18432;
        int tap = r2 / 2048;
        int r3  = r2 % 2048;
        int q   = r3 / 512;
        int r4  = r3 % 512;
        int co  = r4 / 8;
        int j   = r4 % 8;
        int ci = g * 32 + q * 8 + j;
        int base9 = (co * 64 + ci) * 9;
        int base3 = (co * 64 + ci) * 3;
        float v = 0.f;
        if (e == 0) {
            v = w1[base9 + tap];
        } else if (e == 1) {
            if (tap == 4) {
                float s = 0.f;
                #pragma unroll
                for (int k = 0; k < 9; k++) s += w_cd[base9 + k];
                v = w_cd[base9 + 4] - s;
            } else {
                v = w_cd[base9 + tap];
            }
        } else if (e == 2) {
            int m = tap % 3;
            if (m == 0) v = w_hd[base3 + tap / 3];
            else if (m == 2) v = -w_hd[base3 + tap / 3];
        } else if (e == 3) {
            if (tap < 3) v = w_vd[base3 + tap];
            else if (tap >= 6) v = -w_vd[base3 + tap - 6];
        } else {
            const int PERM[9] = {3, 0, 1, 6, 4, 2, 7, 8, 5};
            v = w_ad[base9 + tap] - w_ad[base9 + PERM[tap]];
        }
        wEffB[gid] = f2bf(v);
    } else if (gid < E_ * 36864 + E_ * 64) {
        int jj = gid - E_ * 36864;
        int e = jj / 64, co = jj % 64;
        const float* bs;
        switch (e) {
            case 0: bs = b1; break;
            case 1: bs = b_cd; break;
            case 2: bs = b_hd; break;
            case 3: bs = b_vd; break;
            default: bs = b_ad; break;
        }
        biasEff[jj] = bs[co];
    }
}

// ---------------------------------------------------------------------------
// Kernel 4: MFMA implicit-GEMM conv, two-pass.
// grid 512: bid%8 == b%8 (XCD L2 locality). Block tile: 64co x 8rows x 64cols.
// 4 waves; wave handles rows wave*2+{0,1}. Staging via global_load_lds (16B).
// write_out=0: accumulate Z[b] only.  write_out=1: out = exp(conv+bias)/Z.
__global__ __launch_bounds__(256, 2) void conv_mfma_kernel(
        const uint4* __restrict__ x_t, const unsigned short* __restrict__ wEffB,
        const float* __restrict__ biasEff, const int* __restrict__ expert_idx,
        float* __restrict__ out, float* __restrict__ Z, int write_out) {
    int bid = blockIdx.x;
    int k8 = bid & 7;
    int i = bid >> 3;               // 0..63
    int b = k8 + ((i >> 5) << 3);   // b % 8 == bid % 8
    int rem = i & 31;
    int rg = rem >> 1;              // 0..15, out rows rg*8..+7
    int ch = rem & 1;               // 0/1, out cols ch*64..+63

    int t = threadIdx.x;
    int wave = t >> 6, lane = t & 63;
    int ln = lane & 15, q = lane >> 4;
    int e = expert_idx[b];

    __shared__ __align__(16) unsigned short A_lds[2304 * 8];  // 36864 B: [tap*4+q][co] 16B slots
    __shared__ __align__(16) unsigned short Xs[2640 * 8];     // 42240 B: [xr(10)][qq(4)][66] 16B slots
    __shared__ float zs[4];

    f32x4 acc[4][2][4];
    #pragma unroll
    for (int m = 0; m < 4; m++)
        #pragma unroll
        for (int r = 0; r < 2; r++)
            #pragma unroll
            for (int n = 0; n < 4; n++)
                acc[m][r][n] = (f32x4){0.f, 0.f, 0.f, 0.f};

    const unsigned short* we = wEffB + (size_t)e * 36864;
    const uint4 zero4 = make_uint4(0, 0, 0, 0);

    for (int g = 0; g < 2; g++) {
        // ---- staging: 36 A runs + 40 X runs, wave-strided, all async ----
        for (int r = wave; r < 76; r += 4) {
            if (r < 36) {
                const unsigned short* gp = we + (size_t)g * 18432 + (size_t)(r * 64 + lane) * 8;
                glds16(gp, &A_lds[(r * 64 + lane) * 8]);
            } else {
                int ii = r - 36;
                int xr = ii >> 2;          // 0..9
                int qq = ii & 3;
                int prow = rg * 8 - 1 + xr;
                int sbase = (xr * 4 + qq) * 66;
                if ((unsigned)prow < 128u) {
                    size_t gbase = ((size_t)b * 8 + g * 4 + qq) * PLANE + (size_t)prow * 130 + ch * 64;
                    glds16(&x_t[gbase + lane], &Xs[(sbase + lane) * 8]);
                    if (lane < 2) {
                        uint4 v = x_t[gbase + 64 + lane];
                        *(uint4*)&Xs[(sbase + 64 + lane) * 8] = v;
                    }
                } else {
                    *(uint4*)&Xs[(sbase + lane) * 8] = zero4;
                    if (lane < 2) *(uint4*)&Xs[(sbase + 64 + lane) * 8] = zero4;
                }
            }
        }
        __syncthreads();

        #pragma unroll
        for (int tap = 0; tap < 9; tap++) {
            int dr = tap / 3, dc = tap % 3;
            bf16x8 af[4];
            #pragma unroll
            for (int mt = 0; mt < 4; mt++)
                af[mt] = *(const bf16x8*)&A_lds[((tap * 4 + q) * 64 + mt * 16 + ln) * 8];
            #pragma unroll
            for (int r2 = 0; r2 < 2; r2++) {
                int srow = ((wave * 2 + r2 + dr) * 4 + q) * 66;
                #pragma unroll
                for (int t4 = 0; t4 < 4; t4++) {
                    bf16x8 bfr = *(const bf16x8*)&Xs[(srow + t4 * 16 + ln + dc) * 8];
                    #pragma unroll
                    for (int mt = 0; mt < 4; mt++)
                        acc[mt][r2][t4] = __builtin_amdgcn_mfma_f32_16x16x32_bf16(
                            af[mt], bfr, acc[mt][r2][t4], 0, 0, 0);
                }
            }
        }
        __syncthreads();
    }

    // ---- epilogue ----
    float zinv = write_out ? (1.0f / Z[b]) : 0.f;
    float bsum = 0.f;
    #pragma unroll
    for (int mt = 0; mt < 4; mt++) {
        float4 b4 = *(const float4*)(biasEff + e * 64 + mt * 16 + q * 4);
        const float* bp = (const float*)&b4;
        #pragma unroll
        for (int r2 = 0; r2 < 2; r2++) {
            int orow = rg * 8 + wave * 2 + r2;
            #pragma unroll
            for (int t4 = 0; t4 < 4; t4++) {
                int ocol = ch * 64 + t4 * 16 + ln;
                #pragma unroll
                for (int k = 0; k < 4; k++) {
                    float ev = __expf(acc[mt][r2][t4][k] + bp[k]);
                    if (write_out) {
                        int co = mt * 16 + q * 4 + k;
                        out[(((size_t)b * 64 + co) * 128 + orow) * 128 + ocol] = ev * zinv;
                    } else {
                        bsum += ev;
                    }
                }
            }
        }
    }
    if (!write_out) {
        for (int off = 32; off; off >>= 1) bsum += __shfl_down(bsum, off);
        if (lane == 0) zs[wave] = bsum;
        __syncthreads();
        if (t == 0) atomicAdd(&Z[b], zs[0] + zs[1] + zs[2] + zs[3]);
    }
}

// ---------------------------------------------------------------------------
extern "C" void kernel_launch(void* const* d_in, const int* in_sizes, int n_in,
                              void* d_out, int out_size, void* d_ws, size_t ws_size,
                              hipStream_t stream) {
    const float* x       = (const float*)d_in[0];
    const float* noise   = (const float*)d_in[1];
    const float* w_gate  = (const float*)d_in[2];
    const float* b_gate  = (const float*)d_in[3];
    const float* w_noise = (const float*)d_in[4];
    const float* b_noise = (const float*)d_in[5];
    const float* w1      = (const float*)d_in[6];
    const float* b1      = (const float*)d_in[7];
    const float* w_cd    = (const float*)d_in[8];
    const float* b_cd    = (const float*)d_in[9];
    const float* w_hd    = (const float*)d_in[10];
    const float* b_hd    = (const float*)d_in[11];
    const float* w_vd    = (const float*)d_in[12];
    const float* b_vd    = (const float*)d_in[13];
    const float* w_ad    = (const float*)d_in[14];
    const float* b_ad    = (const float*)d_in[15];

    char* ws = (char*)d_ws;
    unsigned short* wEffB   = (unsigned short*)(ws + WS_WEFFB);
    float*          biasEff = (float*)(ws + WS_BIAS);
    float*          pooled  = (float*)(ws + WS_POOL);
    float*          Zbuf    = (float*)(ws + WS_Z);
    int*            eidx    = (int*)(ws + WS_EIDX);
    uint4*          x_t     = (uint4*)(ws + WS_XT);

    float* out = (float*)d_out;

    hipMemsetAsync(pooled, 0, 4160, stream);  // pooled[1024] + Z[16]

    border_kernel<<<128, 256, 0, stream>>>(x_t);
    transpose_pool_kernel<<<B_ * 128, 256, 0, stream>>>(x, x_t, pooled);
    route_kernel<<<1, 256, 0, stream>>>(pooled, noise, w_gate, b_gate,
                                        w_noise, b_noise, eidx);
    build_w_kernel<<<722, 256, 0, stream>>>(
        w1, w_cd, w_hd, w_vd, w_ad, b1, b_cd, b_hd, b_vd, b_ad, wEffB, biasEff);
    conv_mfma_kernel<<<512, 256, 0, stream>>>(x_t, wEffB, biasEff, eidx, out, Zbuf, 0);
    conv_mfma_kernel<<<512, 256, 0, stream>>>(x_t, wEffB, biasEff, eidx, out, Zbuf, 1);
}